// Round 1
// 74.112 us; speedup vs baseline: 1.0563x; 1.0563x over previous
//
#include <hip/hip_runtime.h>
#include <math.h>

#define NQ 14
#define DIM (1 << NQ)      // 16384 amplitudes
#define NT 512             // 8 waves per block; ~132 KB LDS -> 1 block/CU
#define TA 32              // amplitudes per thread (5-bit tile)
#define NW (NT / 64)
#define PDIM (DIM + DIM / 32)   // padded: one spare cf2 per 32

// ---- compile-time for ----
template <int J> struct IC { static constexpr int v = J; };
template <int N, typename F>
__device__ __forceinline__ void sfor(F&& f) {
    if constexpr (N > 0) { sfor<N - 1>(f); f(IC<N - 1>{}); }
}

// ---- complex amplitude as a 2-wide ext_vector (one 64-bit VGPR pair) ----
typedef float cf2 __attribute__((ext_vector_type(2)));

// ---- packed fp32 gate math (r14/r15-verified VOP3P asm; clang won't lower
// <2 x float> to v_pk_*). cs = (cos,sin) in ONE register pair; op_sel
// broadcasts the needed half. ----
__device__ __forceinline__ cf2 pk_mul_c(cf2 cs, cf2 a) {          // c * a
    cf2 t;
    asm("v_pk_mul_f32 %0, %1, %2 op_sel:[0,0] op_sel_hi:[0,1]"
        : "=v"(t) : "v"(cs), "v"(a));
    return t;
}
__device__ __forceinline__ cf2 pk_mul_s(cf2 cs, cf2 a) {          // s * a
    cf2 t;
    asm("v_pk_mul_f32 %0, %1, %2 op_sel:[1,0] op_sel_hi:[1,1]"
        : "=v"(t) : "v"(cs), "v"(a));
    return t;
}
__device__ __forceinline__ cf2 pk_mul_s_swapneg(cf2 cs, cf2 a) {  // s * (a.y, -a.x)
    cf2 t;
    asm("v_pk_mul_f32 %0, %1, %2 op_sel:[1,1] op_sel_hi:[1,0] neg_hi:[0,1]"
        : "=v"(t) : "v"(cs), "v"(a));
    return t;
}
__device__ __forceinline__ cf2 pk_fma_c(cf2 cs, cf2 a, cf2 b) {   // c*a + b
    cf2 d;
    asm("v_pk_fma_f32 %0, %1, %2, %3 op_sel:[0,0,0] op_sel_hi:[0,1,1]"
        : "=v"(d) : "v"(cs), "v"(a), "v"(b));
    return d;
}
__device__ __forceinline__ cf2 pk_fma_s(cf2 cs, cf2 a, cf2 b) {   // s*a + b
    cf2 d;
    asm("v_pk_fma_f32 %0, %1, %2, %3 op_sel:[1,0,0] op_sel_hi:[1,1,1]"
        : "=v"(d) : "v"(cs), "v"(a), "v"(b));
    return d;
}
__device__ __forceinline__ cf2 pk_fma_c_nb(cf2 cs, cf2 a, cf2 b) { // c*a - b
    cf2 d;
    asm("v_pk_fma_f32 %0, %1, %2, %3 op_sel:[0,0,0] op_sel_hi:[0,1,1] neg_lo:[0,0,1] neg_hi:[0,0,1]"
        : "=v"(d) : "v"(cs), "v"(a), "v"(b));
    return d;
}

// ---- state: 32 INDEPENDENT cf2 SSA values ----
struct St {
    cf2 a0, a1, a2, a3, a4, a5, a6, a7, a8, a9, a10, a11, a12, a13, a14, a15,
        a16, a17, a18, a19, a20, a21, a22, a23, a24, a25, a26, a27, a28, a29, a30, a31;
};
template <int J> __device__ __forceinline__ cf2& amp(St& s);
#define AMP_GET(J) template <> __device__ __forceinline__ cf2& amp<J>(St& s) { return s.a##J; }
AMP_GET(0)  AMP_GET(1)  AMP_GET(2)  AMP_GET(3)  AMP_GET(4)  AMP_GET(5)  AMP_GET(6)  AMP_GET(7)
AMP_GET(8)  AMP_GET(9)  AMP_GET(10) AMP_GET(11) AMP_GET(12) AMP_GET(13) AMP_GET(14) AMP_GET(15)
AMP_GET(16) AMP_GET(17) AMP_GET(18) AMP_GET(19) AMP_GET(20) AMP_GET(21) AMP_GET(22) AMP_GET(23)
AMP_GET(24) AMP_GET(25) AMP_GET(26) AMP_GET(27) AMP_GET(28) AMP_GET(29) AMP_GET(30) AMP_GET(31)

// ---- additive padded layout: phys(idx) = idx + (idx>>5); disjoint-bit sums
// split -> every LDS access = base + compile-time const. ----
__host__ __device__ constexpr int pad(int idx) { return idx + (idx >> 5); }

template <int P0, int P1, int P2, int P3, int P4>
struct Tile5 {
    static constexpr int PMASK = (1 << P0) | (1 << P1) | (1 << P2) | (1 << P3) | (1 << P4);
    static __device__ __forceinline__ int base_idx(int t) {
        int idx = 0, tb = 0;
#pragma unroll
        for (int p = 0; p < NQ; ++p)
            if (!((PMASK >> p) & 1)) { idx |= ((t >> tb) & 1) << p; ++tb; }
        return idx;
    }
    static constexpr int off(int j) {
        return ((j & 1) << P0) | (((j >> 1) & 1) << P1) | (((j >> 2) & 1) << P2) |
               (((j >> 3) & 1) << P3) | (((j >> 4) & 1) << P4);
    }
    static constexpr int poff(int j) { return pad(off(j)); }
};

// qubit q lives at bit position 13-q. Three tiles, used by ALL layers:
using TT1 = Tile5<9, 10, 11, 12, 13>;  // l4..l0 = q0,q1,q2,q3,q4
using TT2 = Tile5<4, 5, 6, 7, 8>;      // l4..l0 = q5,q6,q7,q8,q9
using TT3 = Tile5<13, 0, 1, 2, 3>;     // l4..l0 = q10,q11,q12,q13,q0

// Loads issued pair-interleaved (0,16,1,17,...) so the FIRST gate (cross l4,
// pairs (j,j+16)) can start after 2 returns instead of 17.
template <class T>
__device__ __forceinline__ void load_tile(const cf2* s, int pb, St& st) {
    sfor<TA>([&](auto jc) {
        constexpr int j0 = decltype(jc)::v;
        constexpr int j = (j0 >> 1) | ((j0 & 1) << 4);
        amp<j>(st) = s[pb + T::poff(j)];
    });
}
// Folded load (layers 1-2 only; valid because RX(t) commutes with CNOT(c,t)):
// elements with l4=0 read from pbLo, l4=1 from pbHi (bases carry +/-delta
// when the tid ctrl bit is set), exploiting pad additivity.
template <class T>
__device__ __forceinline__ void load_tile_fold(const cf2* s, int pbLo, int pbHi, St& st) {
    sfor<TA>([&](auto jc) {
        constexpr int j0 = decltype(jc)::v;
        constexpr int j = (j0 >> 1) | ((j0 & 1) << 4);
        amp<j>(st) = s[((j & 16) ? pbHi : pbLo) + T::poff(j)];
    });
}
// Store one 16-amp half (HI = value of local bit l4). Lets the l4=0 half's
// ds_writes drain while the l4=1 half is still computing.
template <class T, int HI>
__device__ __forceinline__ void store_half(cf2* s, int pb, St& st) {
    sfor<TA>([&](auto jc) {
        constexpr int j = decltype(jc)::v;
        if constexpr ((j >> 4) == HI) s[pb + T::poff(j)] = amp<j>(st);
    });
}

// RY: [[c,-s],[s,c]]  (full-tile version; used for cross-group l4 gates)
template <int LB>
__device__ __forceinline__ void g_ry(St& st, cf2 cs) {
    sfor<TA>([&](auto jc) {
        constexpr int j = decltype(jc)::v;
        if constexpr (!(j & (1 << LB))) {
            constexpr int k = j | (1 << LB);
            cf2 aj = amp<j>(st), ak = amp<k>(st);
            amp<j>(st) = pk_fma_c_nb(cs, aj, pk_mul_s(cs, ak));   // c*aj - s*ak
            amp<k>(st) = pk_fma_s(cs, aj, pk_mul_c(cs, ak));      // s*aj + c*ak
        }
    });
}
// RX: [[c,-is],[-is,c]]  (full-tile version)
template <int LB>
__device__ __forceinline__ void g_rx(St& st, cf2 cs) {
    sfor<TA>([&](auto jc) {
        constexpr int j = decltype(jc)::v;
        if constexpr (!(j & (1 << LB))) {
            constexpr int k = j | (1 << LB);
            cf2 aj = amp<j>(st), ak = amp<k>(st);
            amp<j>(st) = pk_fma_c(cs, aj, pk_mul_s_swapneg(cs, ak));
            amp<k>(st) = pk_fma_c(cs, ak, pk_mul_s_swapneg(cs, aj));
        }
    });
}
// ---- group-restricted (l4 == HI) variants: after the cross l4 gates run,
// the two 16-amp halves are independent, enabling store-early pipelining ----
template <int LB, int HI>
__device__ __forceinline__ void g_ry_h(St& st, cf2 cs) {
    sfor<TA>([&](auto jc) {
        constexpr int j = decltype(jc)::v;
        if constexpr (!(j & (1 << LB)) && ((j >> 4) == HI)) {
            constexpr int k = j | (1 << LB);
            cf2 aj = amp<j>(st), ak = amp<k>(st);
            amp<j>(st) = pk_fma_c_nb(cs, aj, pk_mul_s(cs, ak));
            amp<k>(st) = pk_fma_s(cs, aj, pk_mul_c(cs, ak));
        }
    });
}
template <int LB, int HI>
__device__ __forceinline__ void g_rx_h(St& st, cf2 cs) {
    sfor<TA>([&](auto jc) {
        constexpr int j = decltype(jc)::v;
        if constexpr (!(j & (1 << LB)) && ((j >> 4) == HI)) {
            constexpr int k = j | (1 << LB);
            cf2 aj = amp<j>(st), ak = amp<k>(st);
            amp<j>(st) = pk_fma_c(cs, aj, pk_mul_s_swapneg(cs, ak));
            amp<k>(st) = pk_fma_c(cs, ak, pk_mul_s_swapneg(cs, aj));
        }
    });
}
// CNOT both-local restricted to half HI: pure SSA rename (free)
template <int LC, int LT, int HI>
__device__ __forceinline__ void g_cnot_h(St& st) {
    sfor<TA>([&](auto jc) {
        constexpr int j = decltype(jc)::v;
        if constexpr (((j >> LC) & 1) && !((j >> LT) & 1) && ((j >> 4) == HI)) {
            constexpr int k = j | (1 << LT);
            cf2 t = amp<j>(st);
            amp<j>(st) = amp<k>(st);
            amp<k>(st) = t;
        }
    });
}
// CNOT with ctrl = per-thread (divergent) tid bit, target = local bit LT:
// predicated register swap (~64 v_cndmask). Used in layer 0 (embedding RY
// blocks the load-fold since RY does NOT commute with CNOT target).
template <int LT>
__device__ __forceinline__ void g_cnot_pred(St& st, bool ctrl) {
    sfor<TA>([&](auto jc) {
        constexpr int j = decltype(jc)::v;
        if constexpr (!((j >> LT) & 1)) {
            constexpr int k = j | (1 << LT);
            cf2 a = amp<j>(st), b = amp<k>(st);
            amp<j>(st) = ctrl ? b : a;
            amp<k>(st) = ctrl ? a : b;
        }
    });
}

// ============================================================================
// Schedule (8 passes, was 9):
//  * L0-T1 pass is ELIMINATED: before any CNOT leaves {q0..q4}, the state is
//    the product state ⊗ RX(w)·RY(a)|0> on q0..q4 followed by the in-tile CNOT
//    chain (a basis permutation). Each L0-T2 thread's single nonzero input amp
//    is a 5-factor complex product, computed analytically.
//  * Every pass: cross-group l4 gates FIRST (they commute with all l0..l3
//    gates), then the l4=0 half is finished AND STORED before the l4=1 half's
//    gates run -> ds_write drain overlaps VALU instead of bunching at barrier.
//    Equivalence: diag(R0·V, R1·V)·X_l4 = Rename·V_full·X_l4 = original.
// ============================================================================
__global__ void __launch_bounds__(NT) qsim_kernel(const float* __restrict__ x,
                                                  const float* __restrict__ w,
                                                  float* __restrict__ out) {
    __shared__ cf2 sSt[PDIM];            // ~132 KB padded
    __shared__ cf2 sCS[56];              // (cos,sin): [0..13]=RY embed, 14+l*14+q = RX
    __shared__ float sRed[NW][NQ];

    const int tid = threadIdx.x;
    const int b = blockIdx.x;

    if (tid < 14) {
        float th = tanhf(x[b * NQ + tid]) * 1.57079632679489662f;
        cf2 v; v.x = cosf(th); v.y = sinf(th);
        sCS[tid] = v;
    } else if (tid < 56) {
        float th = w[tid - 14] * 0.5f;
        cf2 v; v.x = cosf(th); v.y = sinf(th);
        sCS[tid] = v;
    }

    const int pbT1 = pad(TT1::base_idx(tid));
    const int pbT2 = pad(TT2::base_idx(tid));
    const int pbT3 = pad(TT3::base_idx(tid));
    // fold bases (layers 1-2): T2 target q5 = bit8 -> delta pad(256)=264, ctrl q4 = tid bit4
    const int d2 = ((tid >> 4) & 1) ? 264 : 0;
    const int pbT2lo = pbT2 + d2, pbT2hi = pbT2 - d2;
    // T3 target q10 = bit3 -> delta pad(8)=8, ctrl q9 = tid bit0
    const int d3 = (tid & 1) ? 8 : 0;
    const int pbT3lo = pbT3 + d3, pbT3hi = pbT3 - d3;

    const bool c45 = (tid >> 4) & 1;   // q4 ctrl for layer0 pred-CNOT
    const bool c9A = tid & 1;          // q9 ctrl for layer0 pred-CNOT

    __syncthreads();

    St st;

    // ================= layer 0 (2 passes: T1 folded analytically) ===========
    {   // T2 {q5..q9}: analytic init replaces the whole L0-T1 pass.
        cf2 y5 = sCS[5], y6 = sCS[6], y7 = sCS[7], y8 = sCS[8], y9 = sCS[9];
        cf2 x5 = sCS[19], x6 = sCS[20], x7 = sCS[21], x8 = sCS[22], x9 = sCS[23];

        // Post-(L0-T1) state: nonzero only where idx bits 0..8 == 0, i.e. this
        // thread's amp<0> iff (tid&15)==0. B_q (basis label of qubit q) comes
        // from tid bits 8..4 (positions 13..9); the CNOT chain (q0,q1)..(q3,q4)
        // inverts as b0=B0, b_q = B_q ^ B_{q-1}. amp = prod_q v_q[b_q] with
        // v_q = RX(w0q)·RY(aq)|0> = ( (cx*cy, -sx*sy), (cx*sy, -sx*cy) ).
        const int B0 = (tid >> 8) & 1, B1 = (tid >> 7) & 1, B2 = (tid >> 6) & 1,
                  B3 = (tid >> 5) & 1, B4 = (tid >> 4) & 1;
        const int bb0 = B0, bb1 = B1 ^ B0, bb2 = B2 ^ B1, bb3 = B3 ^ B2, bb4 = B4 ^ B3;
        const int bb[5] = {bb0, bb1, bb2, bb3, bb4};
        float pr = 1.f, pi = 0.f;
#pragma unroll
        for (int q = 0; q < 5; ++q) {
            cf2 ry = sCS[q], rx = sCS[14 + q];
            float re = bb[q] ? rx.x * ry.y : rx.x * ry.x;
            float im = bb[q] ? -rx.y * ry.x : -rx.y * ry.y;
            float nr = pr * re - pi * im;
            pi = pr * im + pi * re;
            pr = nr;
        }
        const bool act = (tid & 15) == 0;

        sfor<TA>([&](auto jc) {
            constexpr int j = decltype(jc)::v;
            cf2 z; z.x = 0.f; z.y = 0.f;
            amp<j>(st) = z;
        });
        amp<0>(st).x = act ? pr : 0.f;
        amp<0>(st).y = act ? pi : 0.f;

        // cross-group gates first: RY/RX on l4=q5, then pred-CNOT(q4,q5)
        g_ry<4>(st, y5); g_rx<4>(st, x5); g_cnot_pred<4>(st, c45);
        // half l4=0: RY/RX q6..q9 + chain renames, store early
        g_ry_h<3,0>(st, y6); g_ry_h<2,0>(st, y7); g_ry_h<1,0>(st, y8); g_ry_h<0,0>(st, y9);
        g_rx_h<3,0>(st, x6); g_rx_h<2,0>(st, x7); g_rx_h<1,0>(st, x8); g_rx_h<0,0>(st, x9);
        g_cnot_h<3,2,0>(st); g_cnot_h<2,1,0>(st); g_cnot_h<1,0,0>(st);
        store_half<TT2, 0>(sSt, pbT2, st);
        // half l4=1
        g_ry_h<3,1>(st, y6); g_ry_h<2,1>(st, y7); g_ry_h<1,1>(st, y8); g_ry_h<0,1>(st, y9);
        g_rx_h<3,1>(st, x6); g_rx_h<2,1>(st, x7); g_rx_h<1,1>(st, x8); g_rx_h<0,1>(st, x9);
        g_cnot_h<4,3,1>(st); g_cnot_h<3,2,1>(st); g_cnot_h<2,1,1>(st); g_cnot_h<1,0,1>(st);
        store_half<TT2, 1>(sSt, pbT2, st);
    }
    __syncthreads();
    {   // T3 {q10-13,q0}: RY/RX q10-13 + pred-CNOT(q9,q10) + chain incl (q13,q0)
        cf2 yA = sCS[10], yB = sCS[11], yC = sCS[12], yD = sCS[13];
        cf2 xA = sCS[24], xB = sCS[25], xC = sCS[26], xD = sCS[27];
        load_tile<TT3>(sSt, pbT3, st);
        g_ry<4>(st, yA); g_rx<4>(st, xA); g_cnot_pred<4>(st, c9A);   // l4 = q10
        g_ry_h<3,0>(st, yB); g_ry_h<2,0>(st, yC); g_ry_h<1,0>(st, yD);
        g_rx_h<3,0>(st, xB); g_rx_h<2,0>(st, xC); g_rx_h<1,0>(st, xD);
        g_cnot_h<3,2,0>(st); g_cnot_h<2,1,0>(st); g_cnot_h<1,0,0>(st);
        store_half<TT3, 0>(sSt, pbT3, st);
        g_ry_h<3,1>(st, yB); g_ry_h<2,1>(st, yC); g_ry_h<1,1>(st, yD);
        g_rx_h<3,1>(st, xB); g_rx_h<2,1>(st, xC); g_rx_h<1,1>(st, xD);
        g_cnot_h<4,3,1>(st); g_cnot_h<3,2,1>(st); g_cnot_h<2,1,1>(st); g_cnot_h<1,0,1>(st);
        store_half<TT3, 1>(sSt, pbT3, st);
    }
    __syncthreads();

    // ================= layers 1,2 (3 passes each) =================
#pragma unroll 1
    for (int l = 1; l < 3; ++l) {
        const int s0 = 14 + l * NQ;
        {   // T1 {q0..q4}
            cf2 c0 = sCS[s0 + 0], c1 = sCS[s0 + 1], c2 = sCS[s0 + 2];
            cf2 c3 = sCS[s0 + 3], c4 = sCS[s0 + 4];
            load_tile<TT1>(sSt, pbT1, st);
            g_rx<4>(st, c0);                                   // cross l4 = q0
            g_rx_h<3,0>(st, c1); g_rx_h<2,0>(st, c2); g_rx_h<1,0>(st, c3); g_rx_h<0,0>(st, c4);
            g_cnot_h<3,2,0>(st); g_cnot_h<2,1,0>(st); g_cnot_h<1,0,0>(st);
            store_half<TT1, 0>(sSt, pbT1, st);
            g_rx_h<3,1>(st, c1); g_rx_h<2,1>(st, c2); g_rx_h<1,1>(st, c3); g_rx_h<0,1>(st, c4);
            g_cnot_h<4,3,1>(st); g_cnot_h<3,2,1>(st); g_cnot_h<2,1,1>(st); g_cnot_h<1,0,1>(st);
            store_half<TT1, 1>(sSt, pbT1, st);
        }
        __syncthreads();
        {   // T2 {q5..q9}: load-fold CNOT(q4,q5)
            cf2 c5 = sCS[s0 + 5], c6 = sCS[s0 + 6], c7 = sCS[s0 + 7];
            cf2 c8 = sCS[s0 + 8], c9 = sCS[s0 + 9];
            load_tile_fold<TT2>(sSt, pbT2lo, pbT2hi, st);
            g_rx<4>(st, c5);                                   // cross l4 = q5
            g_rx_h<3,0>(st, c6); g_rx_h<2,0>(st, c7); g_rx_h<1,0>(st, c8); g_rx_h<0,0>(st, c9);
            g_cnot_h<3,2,0>(st); g_cnot_h<2,1,0>(st); g_cnot_h<1,0,0>(st);
            store_half<TT2, 0>(sSt, pbT2, st);
            g_rx_h<3,1>(st, c6); g_rx_h<2,1>(st, c7); g_rx_h<1,1>(st, c8); g_rx_h<0,1>(st, c9);
            g_cnot_h<4,3,1>(st); g_cnot_h<3,2,1>(st); g_cnot_h<2,1,1>(st); g_cnot_h<1,0,1>(st);
            store_half<TT2, 1>(sSt, pbT2, st);
        }
        __syncthreads();
        {   // T3 {q10..q13,q0}: load-fold CNOT(q9,q10); (q13,q0) in-tile
            cf2 cA = sCS[s0 + 10], cB = sCS[s0 + 11], cC = sCS[s0 + 12], cD = sCS[s0 + 13];
            load_tile_fold<TT3>(sSt, pbT3lo, pbT3hi, st);
            g_rx<4>(st, cA);                                   // cross l4 = q10
            g_rx_h<3,0>(st, cB); g_rx_h<2,0>(st, cC); g_rx_h<1,0>(st, cD);
            g_cnot_h<3,2,0>(st); g_cnot_h<2,1,0>(st); g_cnot_h<1,0,0>(st);
            if (l == 1) store_half<TT3, 0>(sSt, pbT3, st);
            g_rx_h<3,1>(st, cB); g_rx_h<2,1>(st, cC); g_rx_h<1,1>(st, cD);
            g_cnot_h<4,3,1>(st); g_cnot_h<3,2,1>(st); g_cnot_h<2,1,1>(st); g_cnot_h<1,0,1>(st);
            if (l == 1) store_half<TT3, 1>(sSt, pbT3, st);
        }
        if (l == 1) __syncthreads();
    }

    // ====== expvals from final registers (TT3: l0=q0,l1=q13,l2=q12,l3=q11,l4=q10) ======
    float Stot = 0.f, S0 = 0.f, S1 = 0.f, S2 = 0.f, S3 = 0.f, S4 = 0.f;
    sfor<TA>([&](auto jc) {
        constexpr int j = decltype(jc)::v;
        cf2 v = amp<j>(st);
        float pj = v.x * v.x + v.y * v.y;
        Stot += pj;
        S0 += (j & 1)  ? -pj : pj;   // q0
        S1 += (j & 2)  ? -pj : pj;   // q13
        S2 += (j & 4)  ? -pj : pj;   // q12
        S3 += (j & 8)  ? -pj : pj;   // q11
        S4 += (j & 16) ? -pj : pj;   // q10
    });
    float ev[NQ];
    ev[0] = S0; ev[10] = S4; ev[11] = S3; ev[12] = S2; ev[13] = S1;
#pragma unroll
    for (int q = 1; q <= 9; ++q)    // q1..q9 <- tid bit (9-q)
        ev[q] = ((tid >> (9 - q)) & 1) ? -Stot : Stot;

#pragma unroll
    for (int q = 0; q < NQ; ++q) {
#pragma unroll
        for (int o = 32; o > 0; o >>= 1) ev[q] += __shfl_down(ev[q], o);
    }
    const int wv = tid >> 6, ln = tid & 63;
    if (ln == 0) {
#pragma unroll
        for (int q = 0; q < NQ; ++q) sRed[wv][q] = ev[q];
    }
    __syncthreads();
    if (tid < NQ) {
        float acc = 0.f;
#pragma unroll
        for (int k = 0; k < NW; ++k) acc += sRed[k][tid];
        out[b * NQ + tid] = acc;
    }
}

extern "C" void kernel_launch(void* const* d_in, const int* in_sizes, int n_in,
                              void* d_out, int out_size, void* d_ws, size_t ws_size,
                              hipStream_t stream) {
    const float* x = (const float*)d_in[0];   // (256, 14) float32
    const float* w = (const float*)d_in[1];   // (3, 14) float32
    float* out = (float*)d_out;               // (256, 14) float32
    qsim_kernel<<<256, NT, 0, stream>>>(x, w, out);
}

// Round 2
// 71.000 us; speedup vs baseline: 1.1026x; 1.0438x over previous
//
#include <hip/hip_runtime.h>
#include <math.h>

#define NQ 14
#define DIM (1 << NQ)      // 16384 amplitudes
#define NT 512             // 8 waves per block; ~132 KB LDS -> 1 block/CU
#define TA 32              // amplitudes per thread (5-bit tile)
#define NW (NT / 64)
#define PDIM (DIM + DIM / 32)   // padded: one spare cf2 per 32

// ---- compile-time for ----
template <int J> struct IC { static constexpr int v = J; };
template <int N, typename F>
__device__ __forceinline__ void sfor(F&& f) {
    if constexpr (N > 0) { sfor<N - 1>(f); f(IC<N - 1>{}); }
}

// ---- complex amplitude as a 2-wide ext_vector (one 64-bit VGPR pair) ----
typedef float cf2 __attribute__((ext_vector_type(2)));

// ---- packed fp32 gate math (r14/r15-verified VOP3P asm; clang won't lower
// <2 x float> to v_pk_*). cs = (cos,sin) in ONE register pair; op_sel
// broadcasts the needed half. ----
__device__ __forceinline__ cf2 pk_mul_s_swapneg(cf2 cs, cf2 a) {  // s * (a.y, -a.x)
    cf2 t;
    asm("v_pk_mul_f32 %0, %1, %2 op_sel:[1,1] op_sel_hi:[1,0] neg_hi:[0,1]"
        : "=v"(t) : "v"(cs), "v"(a));
    return t;
}
__device__ __forceinline__ cf2 pk_fma_c(cf2 cs, cf2 a, cf2 b) {   // c*a + b
    cf2 d;
    asm("v_pk_fma_f32 %0, %1, %2, %3 op_sel:[0,0,0] op_sel_hi:[0,1,1]"
        : "=v"(d) : "v"(cs), "v"(a), "v"(b));
    return d;
}

// ---- state: 32 INDEPENDENT cf2 SSA values ----
struct St {
    cf2 a0, a1, a2, a3, a4, a5, a6, a7, a8, a9, a10, a11, a12, a13, a14, a15,
        a16, a17, a18, a19, a20, a21, a22, a23, a24, a25, a26, a27, a28, a29, a30, a31;
};
template <int J> __device__ __forceinline__ cf2& amp(St& s);
#define AMP_GET(J) template <> __device__ __forceinline__ cf2& amp<J>(St& s) { return s.a##J; }
AMP_GET(0)  AMP_GET(1)  AMP_GET(2)  AMP_GET(3)  AMP_GET(4)  AMP_GET(5)  AMP_GET(6)  AMP_GET(7)
AMP_GET(8)  AMP_GET(9)  AMP_GET(10) AMP_GET(11) AMP_GET(12) AMP_GET(13) AMP_GET(14) AMP_GET(15)
AMP_GET(16) AMP_GET(17) AMP_GET(18) AMP_GET(19) AMP_GET(20) AMP_GET(21) AMP_GET(22) AMP_GET(23)
AMP_GET(24) AMP_GET(25) AMP_GET(26) AMP_GET(27) AMP_GET(28) AMP_GET(29) AMP_GET(30) AMP_GET(31)

// ---- additive padded layout: phys(idx) = idx + (idx>>5); disjoint-bit sums
// split -> every LDS access = base + compile-time const. ----
__host__ __device__ constexpr int pad(int idx) { return idx + (idx >> 5); }

template <int P0, int P1, int P2, int P3, int P4>
struct Tile5 {
    static constexpr int PMASK = (1 << P0) | (1 << P1) | (1 << P2) | (1 << P3) | (1 << P4);
    static __device__ __forceinline__ int base_idx(int t) {
        int idx = 0, tb = 0;
#pragma unroll
        for (int p = 0; p < NQ; ++p)
            if (!((PMASK >> p) & 1)) { idx |= ((t >> tb) & 1) << p; ++tb; }
        return idx;
    }
    static constexpr int off(int j) {
        return ((j & 1) << P0) | (((j >> 1) & 1) << P1) | (((j >> 2) & 1) << P2) |
               (((j >> 3) & 1) << P3) | (((j >> 4) & 1) << P4);
    }
    static constexpr int poff(int j) { return pad(off(j)); }
};

// qubit q lives at bit position 13-q. Three tiles:
using TT1 = Tile5<9, 10, 11, 12, 13>;  // l4..l0 = q0,q1,q2,q3,q4
using TT2 = Tile5<4, 5, 6, 7, 8>;      // l4..l0 = q5,q6,q7,q8,q9
using TT3 = Tile5<13, 0, 1, 2, 3>;     // l4..l0 = q10,q11,q12,q13,q0

// Loads issued pair-interleaved (0,16,1,17,...) so the FIRST gate (cross l4,
// pairs (j,j+16)) can start after 2 returns instead of 17.
template <class T>
__device__ __forceinline__ void load_tile(const cf2* s, int pb, St& st) {
    sfor<TA>([&](auto jc) {
        constexpr int j0 = decltype(jc)::v;
        constexpr int j = (j0 >> 1) | ((j0 & 1) << 4);
        amp<j>(st) = s[pb + T::poff(j)];
    });
}
// Folded load: elements with l4=0 read from pbLo, l4=1 from pbHi (bases carry
// +/-delta when the tid ctrl bit is set) -> applies CNOT(ctrl,tile-l4) at
// load time (valid: RX on target commutes with CNOT).
template <class T>
__device__ __forceinline__ void load_tile_fold(const cf2* s, int pbLo, int pbHi, St& st) {
    sfor<TA>([&](auto jc) {
        constexpr int j0 = decltype(jc)::v;
        constexpr int j = (j0 >> 1) | ((j0 & 1) << 4);
        amp<j>(st) = s[((j & 16) ? pbHi : pbLo) + T::poff(j)];
    });
}
// Store one 16-amp half (HI = value of local bit l4): lets the l4=0 half's
// ds_writes drain while the l4=1 half is still computing.
template <class T, int HI>
__device__ __forceinline__ void store_half(cf2* s, int pb, St& st) {
    sfor<TA>([&](auto jc) {
        constexpr int j = decltype(jc)::v;
        if constexpr ((j >> 4) == HI) s[pb + T::poff(j)] = amp<j>(st);
    });
}

// RX: [[c,-is],[-is,c]]  (full-tile version; used for cross-group l4 gate)
template <int LB>
__device__ __forceinline__ void g_rx(St& st, cf2 cs) {
    sfor<TA>([&](auto jc) {
        constexpr int j = decltype(jc)::v;
        if constexpr (!(j & (1 << LB))) {
            constexpr int k = j | (1 << LB);
            cf2 aj = amp<j>(st), ak = amp<k>(st);
            amp<j>(st) = pk_fma_c(cs, aj, pk_mul_s_swapneg(cs, ak));
            amp<k>(st) = pk_fma_c(cs, ak, pk_mul_s_swapneg(cs, aj));
        }
    });
}
// group-restricted (l4 == HI) RX: after the cross-l4 gate runs, the halves
// are independent -> store-early pipelining.
template <int LB, int HI>
__device__ __forceinline__ void g_rx_h(St& st, cf2 cs) {
    sfor<TA>([&](auto jc) {
        constexpr int j = decltype(jc)::v;
        if constexpr (!(j & (1 << LB)) && ((j >> 4) == HI)) {
            constexpr int k = j | (1 << LB);
            cf2 aj = amp<j>(st), ak = amp<k>(st);
            amp<j>(st) = pk_fma_c(cs, aj, pk_mul_s_swapneg(cs, ak));
            amp<k>(st) = pk_fma_c(cs, ak, pk_mul_s_swapneg(cs, aj));
        }
    });
}
// CNOT both-local restricted to half HI: pure SSA rename (free)
template <int LC, int LT, int HI>
__device__ __forceinline__ void g_cnot_h(St& st) {
    sfor<TA>([&](auto jc) {
        constexpr int j = decltype(jc)::v;
        if constexpr (((j >> LC) & 1) && !((j >> LT) & 1) && ((j >> 4) == HI)) {
            constexpr int k = j | (1 << LT);
            cf2 t = amp<j>(st);
            amp<j>(st) = amp<k>(st);
            amp<k>(st) = t;
        }
    });
}

// ---- complex helpers for the analytic layer-0 closed form ----
__device__ __forceinline__ cf2 cmul(cf2 a, cf2 b) {
    cf2 r; r.x = a.x * b.x - a.y * b.y; r.y = a.x * b.y + a.y * b.x; return r;
}
// v = RX(w)RY(a)|0>, component b:  v[0]=(cx*cy, -sx*sy), v[1]=(cx*sy, -sx*cy)
__device__ __forceinline__ cf2 v_of(cf2 ry, cf2 rx, int b) {
    cf2 r;
    r.x = b ? rx.x * ry.y : rx.x * ry.x;
    r.y = b ? -(rx.y * ry.x) : -(rx.y * ry.y);
    return r;
}

// ============================================================================
// Schedule (6 passes, was 8):
//  * ALL of layer 0 is a closed form: the CNOT ring is a linear XOR map M on
//    basis labels, and layer 0's input is the product state  ⊗_q v_q  with
//    v_q = RX(w0q)·RY(aq)|0>.  So post-L0 amp(c) = Π_q v_q[b_q(c)], where
//    b = M^{-1}c:  b0=c0^c13, b1=c1^c0^c13, b_k=c_k^c_{k-1} (k>=2).
//    Pass P1 materializes the TT1 tile directly from this product (9-factor
//    per-thread prefix + 5-level binary product tree), then applies L1's
//    T1 gates.  This deletes the L0-T2 and L0-T3 passes AND the L1-T1 load.
//  * Remaining passes unchanged: P2/P3 = L1-T2/T3, P4/P5/P6 = L2-T1/T2/T3
//    (load-fold for cross-tile CNOTs, cross-l4 gate first, store-early halves).
//  * 28 rotations remain in LDS passes; 28/5 -> 6 passes is the 5-wire-tile
//    lower bound.
// ============================================================================
__global__ void __launch_bounds__(NT) qsim_kernel(const float* __restrict__ x,
                                                  const float* __restrict__ w,
                                                  float* __restrict__ out) {
    __shared__ cf2 sSt[PDIM];            // ~132 KB padded
    __shared__ cf2 sCS[56];              // (cos,sin): [0..13]=RY embed, 14+l*14+q = RX
    __shared__ float sRed[NW][NQ];

    const int tid = threadIdx.x;
    const int b = blockIdx.x;

    if (tid < 14) {
        float th = tanhf(x[b * NQ + tid]) * 1.57079632679489662f;
        cf2 v; v.x = cosf(th); v.y = sinf(th);
        sCS[tid] = v;
    } else if (tid < 56) {
        float th = w[tid - 14] * 0.5f;
        cf2 v; v.x = cosf(th); v.y = sinf(th);
        sCS[tid] = v;
    }

    const int pbT1 = pad(TT1::base_idx(tid));
    const int pbT2 = pad(TT2::base_idx(tid));
    const int pbT3 = pad(TT3::base_idx(tid));
    // fold bases: T2 target q5 = bit8 -> delta pad(256)=264, ctrl q4 = tid bit4
    const int d2 = ((tid >> 4) & 1) ? 264 : 0;
    const int pbT2lo = pbT2 + d2, pbT2hi = pbT2 - d2;
    // T3 target q10 = bit3 -> delta pad(8)=8, ctrl q9 = tid bit0
    const int d3 = (tid & 1) ? 8 : 0;
    const int pbT3lo = pbT3 + d3, pbT3hi = pbT3 - d3;

    __syncthreads();

    St st;

    // ===== P1: analytic layer-0 init of TT1 + L1-T1 gates =====
    {
        // TT1 tid bits: position p = tid bit p (p = 0..8).
        const int t0 = tid & 1,        t1 = (tid >> 1) & 1, t2 = (tid >> 2) & 1,
                  t3 = (tid >> 3) & 1, t4 = (tid >> 4) & 1, t5 = (tid >> 5) & 1,
                  t6 = (tid >> 6) & 1, t7 = (tid >> 7) & 1, t8 = (tid >> 8) & 1;
        // c_q = bit at position 13-q:  c5=t8 c6=t7 c7=t6 c8=t5 c9=t4
        //                              c10=t3 c11=t2 c12=t1 c13=t0
        // b_k = c_k ^ c_{k-1} for k=6..13 (tid-only -> shared prefix):
        const int b6 = t7 ^ t8, b7 = t6 ^ t7, b8 = t5 ^ t6, b9 = t4 ^ t5;
        const int b10 = t3 ^ t4, b11 = t2 ^ t3, b12 = t1 ^ t2, b13 = t0 ^ t1;
        cf2 Pref = v_of(sCS[6], sCS[20], b6);
        Pref = cmul(Pref, v_of(sCS[7],  sCS[21], b7));
        Pref = cmul(Pref, v_of(sCS[8],  sCS[22], b8));
        Pref = cmul(Pref, v_of(sCS[9],  sCS[23], b9));
        Pref = cmul(Pref, v_of(sCS[10], sCS[24], b10));
        Pref = cmul(Pref, v_of(sCS[11], sCS[25], b11));
        Pref = cmul(Pref, v_of(sCS[12], sCS[26], b12));
        Pref = cmul(Pref, v_of(sCS[13], sCS[27], b13));
        // Reg bits (TT1): c0=j4 c1=j3 c2=j2 c3=j1 c4=j0.
        //   b0 = j4^t0          -> w0[j4],     w0[x] = v0[x^t0]
        //   b1 = j3^j4^t0       -> w1[j3^j4],  w1[x] = v1[x^t0]
        //   b2 = j2^j3, b3 = j1^j2, b4 = j0^j1
        //   b5 = t8^j0          -> w5[j0],     w5[x] = v5[x^t8]
        cf2 w0[2] = { v_of(sCS[0], sCS[14], t0),     v_of(sCS[0], sCS[14], 1 ^ t0) };
        cf2 w1[2] = { v_of(sCS[1], sCS[15], t0),     v_of(sCS[1], sCS[15], 1 ^ t0) };
        cf2 v2[2] = { v_of(sCS[2], sCS[16], 0),      v_of(sCS[2], sCS[16], 1) };
        cf2 v3[2] = { v_of(sCS[3], sCS[17], 0),      v_of(sCS[3], sCS[17], 1) };
        cf2 v4[2] = { v_of(sCS[4], sCS[18], 0),      v_of(sCS[4], sCS[18], 1) };
        cf2 w5[2] = { v_of(sCS[5], sCS[19], t8),     v_of(sCS[5], sCS[19], 1 ^ t8) };
        // u[(j1<<1)|j0] = v4[j0^j1] * w5[j0]
        cf2 u[4] = { cmul(v4[0], w5[0]), cmul(v4[1], w5[1]),
                     cmul(v4[1], w5[0]), cmul(v4[0], w5[1]) };
        // product tree (all indices compile-time -> pure SSA, no scratch)
        cf2 tA[2], tB[4], tC[8], tD[16];
        sfor<2>([&](auto ic) {
            constexpr int i = decltype(ic)::v;
            tA[i] = cmul(Pref, w0[i]);
        });
        sfor<4>([&](auto ic) {
            constexpr int i = decltype(ic)::v;           // i = (j4<<1)|j3
            constexpr int j4 = i >> 1, j3 = i & 1;
            tB[i] = cmul(tA[j4], w1[j3 ^ j4]);
        });
        sfor<8>([&](auto ic) {
            constexpr int i = decltype(ic)::v;           // i = (j4,j3,j2)
            constexpr int j3 = (i >> 1) & 1, j2 = i & 1;
            tC[i] = cmul(tB[i >> 1], v2[j2 ^ j3]);
        });
        sfor<16>([&](auto ic) {
            constexpr int i = decltype(ic)::v;           // i = (j4,j3,j2,j1)
            constexpr int j2 = (i >> 1) & 1, j1 = i & 1;
            tD[i] = cmul(tC[i >> 1], v3[j1 ^ j2]);
        });
        sfor<TA>([&](auto jc) {
            constexpr int j = decltype(jc)::v;
            constexpr int j0 = j & 1, j1 = (j >> 1) & 1;
            amp<j>(st) = cmul(tD[j >> 1], u[(j1 << 1) | j0]);
        });

        // L1-T1 gates: RX q0..q4 (l4..l0) + CNOT(q0,q1)..(q3,q4)
        g_rx<4>(st, sCS[28 + 0]);                        // cross-l4 = q0
        g_rx_h<3, 0>(st, sCS[28 + 1]); g_rx_h<2, 0>(st, sCS[28 + 2]);
        g_rx_h<1, 0>(st, sCS[28 + 3]); g_rx_h<0, 0>(st, sCS[28 + 4]);
        g_cnot_h<3, 2, 0>(st); g_cnot_h<2, 1, 0>(st); g_cnot_h<1, 0, 0>(st);
        store_half<TT1, 0>(sSt, pbT1, st);
        g_rx_h<3, 1>(st, sCS[28 + 1]); g_rx_h<2, 1>(st, sCS[28 + 2]);
        g_rx_h<1, 1>(st, sCS[28 + 3]); g_rx_h<0, 1>(st, sCS[28 + 4]);
        g_cnot_h<4, 3, 1>(st); g_cnot_h<3, 2, 1>(st); g_cnot_h<2, 1, 1>(st); g_cnot_h<1, 0, 1>(st);
        store_half<TT1, 1>(sSt, pbT1, st);
    }
    __syncthreads();

    // ===== P2..P6 =====
#pragma unroll 1
    for (int l = 1; l < 3; ++l) {
        const int s0 = 14 + l * NQ;
        if (l == 2) {   // P4: L2-T1 {q0..q4}
            cf2 c0 = sCS[s0 + 0], c1 = sCS[s0 + 1], c2 = sCS[s0 + 2];
            cf2 c3 = sCS[s0 + 3], c4 = sCS[s0 + 4];
            load_tile<TT1>(sSt, pbT1, st);
            g_rx<4>(st, c0);                                   // cross l4 = q0
            g_rx_h<3,0>(st, c1); g_rx_h<2,0>(st, c2); g_rx_h<1,0>(st, c3); g_rx_h<0,0>(st, c4);
            g_cnot_h<3,2,0>(st); g_cnot_h<2,1,0>(st); g_cnot_h<1,0,0>(st);
            store_half<TT1, 0>(sSt, pbT1, st);
            g_rx_h<3,1>(st, c1); g_rx_h<2,1>(st, c2); g_rx_h<1,1>(st, c3); g_rx_h<0,1>(st, c4);
            g_cnot_h<4,3,1>(st); g_cnot_h<3,2,1>(st); g_cnot_h<2,1,1>(st); g_cnot_h<1,0,1>(st);
            store_half<TT1, 1>(sSt, pbT1, st);
            __syncthreads();
        }
        {   // P2/P5: T2 {q5..q9}: load-fold CNOT(q4,q5)
            cf2 c5 = sCS[s0 + 5], c6 = sCS[s0 + 6], c7 = sCS[s0 + 7];
            cf2 c8 = sCS[s0 + 8], c9 = sCS[s0 + 9];
            load_tile_fold<TT2>(sSt, pbT2lo, pbT2hi, st);
            g_rx<4>(st, c5);                                   // cross l4 = q5
            g_rx_h<3,0>(st, c6); g_rx_h<2,0>(st, c7); g_rx_h<1,0>(st, c8); g_rx_h<0,0>(st, c9);
            g_cnot_h<3,2,0>(st); g_cnot_h<2,1,0>(st); g_cnot_h<1,0,0>(st);
            store_half<TT2, 0>(sSt, pbT2, st);
            g_rx_h<3,1>(st, c6); g_rx_h<2,1>(st, c7); g_rx_h<1,1>(st, c8); g_rx_h<0,1>(st, c9);
            g_cnot_h<4,3,1>(st); g_cnot_h<3,2,1>(st); g_cnot_h<2,1,1>(st); g_cnot_h<1,0,1>(st);
            store_half<TT2, 1>(sSt, pbT2, st);
        }
        __syncthreads();
        {   // P3/P6: T3 {q10..q13,q0}: load-fold CNOT(q9,q10); (q13,q0) in-tile
            cf2 cA = sCS[s0 + 10], cB = sCS[s0 + 11], cC = sCS[s0 + 12], cD = sCS[s0 + 13];
            load_tile_fold<TT3>(sSt, pbT3lo, pbT3hi, st);
            g_rx<4>(st, cA);                                   // cross l4 = q10
            g_rx_h<3,0>(st, cB); g_rx_h<2,0>(st, cC); g_rx_h<1,0>(st, cD);
            g_cnot_h<3,2,0>(st); g_cnot_h<2,1,0>(st); g_cnot_h<1,0,0>(st);
            if (l == 1) store_half<TT3, 0>(sSt, pbT3, st);
            g_rx_h<3,1>(st, cB); g_rx_h<2,1>(st, cC); g_rx_h<1,1>(st, cD);
            g_cnot_h<4,3,1>(st); g_cnot_h<3,2,1>(st); g_cnot_h<2,1,1>(st); g_cnot_h<1,0,1>(st);
            if (l == 1) store_half<TT3, 1>(sSt, pbT3, st);
        }
        if (l == 1) __syncthreads();
    }

    // ====== expvals from final registers (TT3: l0=q0,l1=q13,l2=q12,l3=q11,l4=q10) ======
    float Stot = 0.f, S0 = 0.f, S1 = 0.f, S2 = 0.f, S3 = 0.f, S4 = 0.f;
    sfor<TA>([&](auto jc) {
        constexpr int j = decltype(jc)::v;
        cf2 v = amp<j>(st);
        float pj = v.x * v.x + v.y * v.y;
        Stot += pj;
        S0 += (j & 1)  ? -pj : pj;   // q0
        S1 += (j & 2)  ? -pj : pj;   // q13
        S2 += (j & 4)  ? -pj : pj;   // q12
        S3 += (j & 8)  ? -pj : pj;   // q11
        S4 += (j & 16) ? -pj : pj;   // q10
    });
    float ev[NQ];
    ev[0] = S0; ev[10] = S4; ev[11] = S3; ev[12] = S2; ev[13] = S1;
#pragma unroll
    for (int q = 1; q <= 9; ++q)    // q1..q9 <- tid bit (9-q)
        ev[q] = ((tid >> (9 - q)) & 1) ? -Stot : Stot;

#pragma unroll
    for (int q = 0; q < NQ; ++q) {
#pragma unroll
        for (int o = 32; o > 0; o >>= 1) ev[q] += __shfl_down(ev[q], o);
    }
    const int wv = tid >> 6, ln = tid & 63;
    if (ln == 0) {
#pragma unroll
        for (int q = 0; q < NQ; ++q) sRed[wv][q] = ev[q];
    }
    __syncthreads();
    if (tid < NQ) {
        float acc = 0.f;
#pragma unroll
        for (int k = 0; k < NW; ++k) acc += sRed[k][tid];
        out[b * NQ + tid] = acc;
    }
}

extern "C" void kernel_launch(void* const* d_in, const int* in_sizes, int n_in,
                              void* d_out, int out_size, void* d_ws, size_t ws_size,
                              hipStream_t stream) {
    const float* x = (const float*)d_in[0];   // (256, 14) float32
    const float* w = (const float*)d_in[1];   // (3, 14) float32
    float* out = (float*)d_out;               // (256, 14) float32
    qsim_kernel<<<256, NT, 0, stream>>>(x, w, out);
}